// Round 2
// baseline (997.684 us; speedup 1.0000x reference)
//
#include <hip/hip_runtime.h>
#include <stdint.h>

// Problem constants
#define Bb  8
#define Ss  4096
#define Dd  512
#define DIi 2048
#define Mm  (Bb*Ss)   // 32768 rows

typedef unsigned short u16;
typedef __bf16 bf16x8 __attribute__((ext_vector_type(8)));
typedef float  f32x4  __attribute__((ext_vector_type(4)));

__device__ __forceinline__ float bfu(unsigned int u) {
  return __uint_as_float((u & 0xffffu) << 16);
}
__device__ __forceinline__ u16 f2bu(float f) {
  unsigned int x = __float_as_uint(f);
  return (u16)((x + 0x7fffu + ((x >> 16) & 1u)) >> 16);  // RNE
}

__global__ __launch_bounds__(256) void zero_f32(float* __restrict__ p, int n) {
  int i = blockIdx.x * 256 + threadIdx.x;
  if (i < n) p[i] = 0.f;
}

__global__ __launch_bounds__(256) void f32_to_bf16_vec(const float* __restrict__ in,
                                                       u16* __restrict__ outp, long n4) {
  long i = (long)blockIdx.x * 256 + threadIdx.x;
  const long st = (long)gridDim.x * 256;
  for (; i < n4; i += st) {
    float4 v = ((const float4*)in)[i];
    ushort4 o;
    o.x = f2bu(v.x); o.y = f2bu(v.y); o.z = f2bu(v.z); o.w = f2bu(v.w);
    ((ushort4*)outp)[i] = o;
  }
}

// transpose f32 [K][N] -> bf16 [N][K]
__global__ void transpose_f32_bf16(const float* __restrict__ W, u16* __restrict__ Wt,
                                   int K, int N) {
  __shared__ float t[32][33];
  const int n0 = blockIdx.x * 32, k0 = blockIdx.y * 32;
  const int tx = threadIdx.x, ty = threadIdx.y;  // 32 x 8
#pragma unroll
  for (int i = 0; i < 32; i += 8)
    t[ty + i][tx] = W[(long)(k0 + ty + i) * N + n0 + tx];
  __syncthreads();
#pragma unroll
  for (int i = 0; i < 32; i += 8)
    Wt[(long)(n0 + ty + i) * K + k0 + tx] = f2bu(t[tx][ty + i]);
}

// ---------------- unified MFMA GEMM (m97 structure, 128x128 tile) ----------------
// C[M,N] = A[M,K] @ Bt[N,K]^T, bf16 in, f32 acc. MODE selects epilogue / dual-B.
#define BM 128
#define BN 128
#define BK 32

enum { M_PROJKQ = 0, M_KV = 1, M_APREP = 2, M_WO = 3, M_FFN1 = 4, M_FFN2 = 5 };

#define GLL(src, dst) \
  __builtin_amdgcn_global_load_lds((const __attribute__((address_space(1))) unsigned int*)(src), \
                                   (__attribute__((address_space(3))) unsigned int*)(dst), 16, 0, 0)

template<int MODE>
__global__ __launch_bounds__(256) void mega(
    const u16* __restrict__ A, const u16* __restrict__ Bt, const u16* __restrict__ Bt2,
    int M, int N, int K,
    u16* __restrict__ Ybf, float* __restrict__ Yf,
    const float* __restrict__ resf, const u16* __restrict__ resb,
    const float* __restrict__ bias,
    const u16* __restrict__ Kst, float* __restrict__ nksq, float* __restrict__ nqsq,
    const float* __restrict__ kvin, float* __restrict__ kvout)
{
  constexpr bool DUALB = (MODE == M_PROJKQ);
  __shared__ u16 As[BM * BK];                 // 8 KB
  __shared__ u16 Bs[BN * BK];                 // 8 KB
  __shared__ u16 Bs2[DUALB ? (BN * BK) : 64]; // 8 KB when dual

  const int tid  = threadIdx.x;
  const int lane = tid & 63;
  const int w    = tid >> 6;
  const int wr = w >> 1, wc = w & 1;          // 2x2 wave grid, 64x64 per wave
  const int l15 = lane & 15, lg = lane >> 4;
  const long bm0 = (long)blockIdx.y * BM;
  const long bn0 = (long)blockIdx.x * BN;

  // staging: 512 chunks of 16B per operand tile; thread t does chunks t and t+256
  const int c0 = tid, c1 = tid + 256;
  const u16* aS0 = A  + (bm0 + (c0 >> 2)) * K + (c0 & 3) * 8;
  const u16* aS1 = A  + (bm0 + (c1 >> 2)) * K + (c1 & 3) * 8;
  const u16* bS0 = Bt + (bn0 + (c0 >> 2)) * K + (c0 & 3) * 8;
  const u16* bS1 = Bt + (bn0 + (c1 >> 2)) * K + (c1 & 3) * 8;
  const u16* b2S0 = DUALB ? (Bt2 + (bn0 + (c0 >> 2)) * K + (c0 & 3) * 8) : nullptr;
  const u16* b2S1 = DUALB ? (Bt2 + (bn0 + (c1 >> 2)) * K + (c1 & 3) * 8) : nullptr;
  u16* aD0 = As + w * 512;          // wave-uniform LDS bases (HW adds lane*16B)
  u16* aD1 = As + 2048 + w * 512;
  u16* bD0 = Bs + w * 512;
  u16* bD1 = Bs + 2048 + w * 512;
  u16* b2D0 = DUALB ? (Bs2 + w * 512) : nullptr;
  u16* b2D1 = DUALB ? (Bs2 + 2048 + w * 512) : nullptr;

  f32x4 acc[4][4] = {};
  f32x4 acc2[4][4];
  if constexpr (DUALB) {
#pragma unroll
    for (int m = 0; m < 4; ++m)
#pragma unroll
      for (int n = 0; n < 4; ++n) acc2[m][n] = (f32x4){0.f, 0.f, 0.f, 0.f};
  }

  for (int k0 = 0; k0 < K; k0 += BK) {
    GLL(aS0 + k0, aD0);
    GLL(aS1 + k0, aD1);
    GLL(bS0 + k0, bD0);
    GLL(bS1 + k0, bD1);
    if constexpr (DUALB) { GLL(b2S0 + k0, b2D0); GLL(b2S1 + k0, b2D1); }
    __syncthreads();   // drains vmcnt for staging, then barrier

    bf16x8 af[4], bfv[4], bfv2[4];
#pragma unroll
    for (int m = 0; m < 4; ++m)
      af[m] = *(const bf16x8*)(As + (wr * 64 + m * 16 + l15) * BK + lg * 8);
#pragma unroll
    for (int n = 0; n < 4; ++n)
      bfv[n] = *(const bf16x8*)(Bs + (wc * 64 + n * 16 + l15) * BK + lg * 8);
    if constexpr (DUALB) {
#pragma unroll
      for (int n = 0; n < 4; ++n)
        bfv2[n] = *(const bf16x8*)(Bs2 + (wc * 64 + n * 16 + l15) * BK + lg * 8);
    }
#pragma unroll
    for (int m = 0; m < 4; ++m)
#pragma unroll
      for (int n = 0; n < 4; ++n) {
        acc[m][n] = __builtin_amdgcn_mfma_f32_16x16x32_bf16(af[m], bfv[n], acc[m][n], 0, 0, 0);
        if constexpr (DUALB)
          acc2[m][n] = __builtin_amdgcn_mfma_f32_16x16x32_bf16(af[m], bfv2[n], acc2[m][n], 0, 0, 0);
      }
    __syncthreads();   // LDS reads done before next stage overwrites
  }

  // C/D layout: col = lane&15, row = (lane>>4)*4 + r  [verified m89/m91]
  const int b = (int)(bm0 >> 12);   // row / Ss (block never spans batches)

  if constexpr (MODE == M_PROJKQ) {
    // store K tile; accumulate per-row sum of squares for k (acc) and q (acc2)
    float sk[16], sq[16];
#pragma unroll
    for (int i = 0; i < 16; ++i) { sk[i] = 0.f; sq[i] = 0.f; }
#pragma unroll
    for (int m = 0; m < 4; ++m) {
      const long row0 = bm0 + wr * 64 + m * 16 + lg * 4;
#pragma unroll
      for (int n = 0; n < 4; ++n) {
        const long col = bn0 + wc * 64 + n * 16 + l15;
#pragma unroll
        for (int r = 0; r < 4; ++r) {
          const float kvl = acc[m][n][r];
          const float qvl = acc2[m][n][r];
          Ybf[(row0 + r) * N + col] = f2bu(kvl);
          sk[m * 4 + r] += kvl * kvl;
          sq[m * 4 + r] += qvl * qvl;
        }
      }
    }
#pragma unroll
    for (int i = 0; i < 16; ++i) {
#pragma unroll
      for (int off = 1; off < 16; off <<= 1) {
        sk[i] += __shfl_xor(sk[i], off, 64);
        sq[i] += __shfl_xor(sq[i], off, 64);
      }
    }
    if (l15 == 0) {
#pragma unroll
      for (int m = 0; m < 4; ++m)
#pragma unroll
        for (int r = 0; r < 4; ++r) {
          const long row = bm0 + wr * 64 + m * 16 + lg * 4 + r;
          atomicAdd(&nksq[row], sk[m * 4 + r]);
          atomicAdd(&nqsq[row], sq[m * 4 + r]);
        }
    }
  } else if constexpr (MODE == M_KV) {
    // acc = V tile; read stored K tile, scale rows by 1/||k||, reduce over rows
    float rnv[16];
#pragma unroll
    for (int m = 0; m < 4; ++m)
#pragma unroll
      for (int r = 0; r < 4; ++r) {
        const long row = bm0 + wr * 64 + m * 16 + lg * 4 + r;
        rnv[m * 4 + r] = 1.f / fmaxf(sqrtf(nksq[row]), 1e-12f);
      }
    float cs[4] = {0.f, 0.f, 0.f, 0.f};
#pragma unroll
    for (int m = 0; m < 4; ++m) {
      const long row0 = bm0 + wr * 64 + m * 16 + lg * 4;
#pragma unroll
      for (int n = 0; n < 4; ++n) {
        const long col = bn0 + wc * 64 + n * 16 + l15;
#pragma unroll
        for (int r = 0; r < 4; ++r)
          cs[n] += bfu(Kst[(row0 + r) * N + col]) * rnv[m * 4 + r] * acc[m][n][r];
      }
    }
#pragma unroll
    for (int n = 0; n < 4; ++n) {
      cs[n] += __shfl_xor(cs[n], 16, 64);
      cs[n] += __shfl_xor(cs[n], 32, 64);
    }
    if (lane < 16) {
#pragma unroll
      for (int n = 0; n < 4; ++n) {
        const long col = bn0 + wc * 64 + n * 16 + l15;
        atomicAdd(&kvout[(long)b * DIi + col], cs[n]);
      }
    }
  } else {
#pragma unroll
    for (int m = 0; m < 4; ++m) {
      const long row0 = bm0 + wr * 64 + m * 16 + lg * 4;
#pragma unroll
      for (int n = 0; n < 4; ++n) {
        const long col = bn0 + wc * 64 + n * 16 + l15;
        float kvv;
        if constexpr (MODE == M_APREP) kvv = kvin[(long)b * DIi + col];
#pragma unroll
        for (int r = 0; r < 4; ++r) {
          const long idx = (row0 + r) * N + col;
          const float v = acc[m][n][r];
          if constexpr (MODE == M_APREP) {
            const float rq = 1.f / fmaxf(sqrtf(nqsq[row0 + r]), 1e-12f);
            Ybf[idx] = f2bu(v * rq * kvv);
          } else if constexpr (MODE == M_WO) {
            Ybf[idx] = f2bu(v + resf[idx]);
          } else if constexpr (MODE == M_FFN1) {
            float o = v + bias[col];
            o = o > 0.f ? o : 0.f;
            Ybf[idx] = f2bu(o);
          } else {  // M_FFN2
            Yf[idx] = v + bias[col] + bfu(resb[idx]);
          }
        }
      }
    }
  }
}

extern "C" void kernel_launch(void* const* d_in, const int* in_sizes, int n_in,
                              void* d_out, int out_size, void* d_ws, size_t ws_size,
                              hipStream_t stream) {
  const float* x  = (const float*)d_in[0];
  const float* wq = (const float*)d_in[1];
  const float* wk = (const float*)d_in[2];
  const float* wv = (const float*)d_in[3];
  const float* wo = (const float*)d_in[4];
  const float* w1 = (const float*)d_in[5];
  const float* b1 = (const float*)d_in[6];
  const float* w2 = (const float*)d_in[7];
  const float* b2 = (const float*)d_in[8];
  float* out = (float*)d_out;

  // workspace carve-up: ~180 MB peak
  char* p = (char*)d_ws;
  auto take = [&](size_t bytes) {
    char* r = p; p += (bytes + 255) & ~(size_t)255; return r;
  };
  u16*   xb   = (u16*)take((size_t)Mm * Dd * 2);    // x bf16; later reused as attn bf16
  u16*   wkT  = (u16*)take((size_t)DIi * Dd * 2);
  u16*   wqT  = (u16*)take((size_t)DIi * Dd * 2);
  u16*   wvT  = (u16*)take((size_t)DIi * Dd * 2);
  u16*   woT  = (u16*)take((size_t)Dd * DIi * 2);
  u16*   w1T  = (u16*)take((size_t)DIi * Dd * 2);
  u16*   w2T  = (u16*)take((size_t)Dd * DIi * 2);
  u16*   buf1 = (u16*)take((size_t)Mm * DIi * 2);   // K, then Aprep, then h
  float* nksq = (float*)take((size_t)Mm * 4);
  float* nqsq = (float*)take((size_t)Mm * 4);
  float* kvp  = (float*)take((size_t)Bb * DIi * 4);
  (void)ws_size; (void)in_sizes; (void)n_in; (void)out_size;

  const dim3 tpB(32, 8);

  // per-call zeroing of atomic accumulators
  zero_f32<<<(Mm + 255) / 256, 256, 0, stream>>>(nksq, Mm);
  zero_f32<<<(Mm + 255) / 256, 256, 0, stream>>>(nqsq, Mm);
  zero_f32<<<(Bb * DIi + 255) / 256, 256, 0, stream>>>(kvp, Bb * DIi);

  // conversions
  f32_to_bf16_vec<<<2048, 256, 0, stream>>>(x, xb, (long)Mm * Dd / 4);
  transpose_f32_bf16<<<dim3(DIi / 32, Dd / 32), tpB, 0, stream>>>(wk, wkT, Dd, DIi);
  transpose_f32_bf16<<<dim3(DIi / 32, Dd / 32), tpB, 0, stream>>>(wq, wqT, Dd, DIi);
  transpose_f32_bf16<<<dim3(DIi / 32, Dd / 32), tpB, 0, stream>>>(wv, wvT, Dd, DIi);
  transpose_f32_bf16<<<dim3(Dd / 32, DIi / 32), tpB, 0, stream>>>(wo, woT, DIi, Dd);
  transpose_f32_bf16<<<dim3(DIi / 32, Dd / 32), tpB, 0, stream>>>(w1, w1T, Dd, DIi);
  transpose_f32_bf16<<<dim3(Dd / 32, DIi / 32), tpB, 0, stream>>>(w2, w2T, DIi, Dd);

  // K (stored bf16 -> buf1) + Q (sumsq only); per-row sumsq of both via atomics
  mega<M_PROJKQ><<<dim3(DIi / BN, Mm / BM), 256, 0, stream>>>(
      xb, wkT, wqT, Mm, DIi, Dd, buf1, nullptr, nullptr, nullptr, nullptr,
      nullptr, nksq, nqsq, nullptr, nullptr);

  // V tiles + fold 1/||k|| and reduce over rows -> kv[b,e]
  mega<M_KV><<<dim3(DIi / BN, Mm / BM), 256, 0, stream>>>(
      xb, wvT, nullptr, Mm, DIi, Dd, nullptr, nullptr, nullptr, nullptr, nullptr,
      buf1, nksq, nullptr, nullptr, kvp);

  // recompute Q; Aprep = bf16(q * rsqrt(nqsq) * kv[b,col]) -> buf1 (K dead)
  mega<M_APREP><<<dim3(DIi / BN, Mm / BM), 256, 0, stream>>>(
      xb, wqT, nullptr, Mm, DIi, Dd, buf1, nullptr, nullptr, nullptr, nullptr,
      nullptr, nullptr, nqsq, kvp, nullptr);

  // attn = Aprep @ wo + x -> bf16 into xb slot (xb dead)
  mega<M_WO><<<dim3(Dd / BN, Mm / BM), 256, 0, stream>>>(
      buf1, woT, nullptr, Mm, Dd, DIi, xb, nullptr, x, nullptr, nullptr,
      nullptr, nullptr, nullptr, nullptr, nullptr);

  // h = relu(attn @ w1 + b1) -> buf1 (Aprep dead)
  mega<M_FFN1><<<dim3(DIi / BN, Mm / BM), 256, 0, stream>>>(
      xb, w1T, nullptr, Mm, DIi, Dd, buf1, nullptr, nullptr, nullptr, b1,
      nullptr, nullptr, nullptr, nullptr, nullptr);

  // out = h @ w2 + b2 + attn
  mega<M_FFN2><<<dim3(Dd / BN, Mm / BM), 256, 0, stream>>>(
      buf1, w2T, nullptr, Mm, Dd, DIi, nullptr, out, nullptr, xb, b2,
      nullptr, nullptr, nullptr, nullptr, nullptr);
}

// Round 3
// 798.740 us; speedup vs baseline: 1.2491x; 1.2491x over previous
//
#include <hip/hip_runtime.h>
#include <stdint.h>

// Problem constants
#define Bb  8
#define Ss  4096
#define Dd  512
#define DIi 2048
#define Mm  (Bb*Ss)   // 32768 rows

typedef unsigned short u16;
typedef __bf16 bf16x8 __attribute__((ext_vector_type(8)));
typedef float  f32x4  __attribute__((ext_vector_type(4)));

__device__ __forceinline__ float bfu(unsigned int u) {
  return __uint_as_float((u & 0xffffu) << 16);
}
__device__ __forceinline__ u16 f2bu(float f) {
  unsigned int x = __float_as_uint(f);
  return (u16)((x + 0x7fffu + ((x >> 16) & 1u)) >> 16);  // RNE
}

__global__ __launch_bounds__(256) void zero_f32(float* __restrict__ p, int n) {
  int i = blockIdx.x * 256 + threadIdx.x;
  if (i < n) p[i] = 0.f;
}

__global__ __launch_bounds__(256) void f32_to_bf16_vec(const float* __restrict__ in,
                                                       u16* __restrict__ outp, long n4) {
  long i = (long)blockIdx.x * 256 + threadIdx.x;
  const long st = (long)gridDim.x * 256;
  for (; i < n4; i += st) {
    float4 v = ((const float4*)in)[i];
    ushort4 o;
    o.x = f2bu(v.x); o.y = f2bu(v.y); o.z = f2bu(v.z); o.w = f2bu(v.w);
    ((ushort4*)outp)[i] = o;
  }
}

// transpose f32 [K][N] -> bf16 [N][K]
__global__ void transpose_f32_bf16(const float* __restrict__ W, u16* __restrict__ Wt,
                                   int K, int N) {
  __shared__ float t[32][33];
  const int n0 = blockIdx.x * 32, k0 = blockIdx.y * 32;
  const int tx = threadIdx.x, ty = threadIdx.y;  // 32 x 8
#pragma unroll
  for (int i = 0; i < 32; i += 8)
    t[ty + i][tx] = W[(long)(k0 + ty + i) * N + n0 + tx];
  __syncthreads();
#pragma unroll
  for (int i = 0; i < 32; i += 8)
    Wt[(long)(n0 + ty + i) * K + k0 + tx] = f2bu(t[tx][ty + i]);
}

// ---- Aprep (in place): q[m,e] <- bf16( q[m,e] * rsqrt(nqsq[m]) * kv[b(m),e] ) ----
__global__ __launch_bounds__(256) void prep_attn(u16* __restrict__ qb,
                                                 const float* __restrict__ kv,
                                                 const float* __restrict__ nqsq) {
  long i = (long)blockIdx.x * 256 + threadIdx.x;
  const long tot = (long)Mm * DIi / 4;
  const long st = (long)gridDim.x * 256;
  for (; i < tot; i += st) {
    const long idx = i * 4;
    const int m = (int)(idx >> 11);          // / DIi
    const int e = (int)(idx & (DIi - 1));
    const int b = m >> 12;                   // / Ss
    const float r = 1.f / fmaxf(sqrtf(nqsq[m]), 1e-12f);
    ushort4 qu = *(const ushort4*)(qb + idx);
    float4 kve = *(const float4*)(kv + (long)b * DIi + e);
    ushort4 o;
    o.x = f2bu(bfu(qu.x) * kve.x * r);
    o.y = f2bu(bfu(qu.y) * kve.y * r);
    o.z = f2bu(bfu(qu.z) * kve.z * r);
    o.w = f2bu(bfu(qu.w) * kve.w * r);
    *(ushort4*)(qb + idx) = o;
  }
}

// ---------------- unified MFMA GEMM (m97 structure, 128x128 tile) ----------------
// C[M,N] = A[M,K] @ Bt[N,K]^T, bf16 in, f32 acc. MODE selects epilogue.
#define BM 128
#define BN 128
#define BK 32

enum { M_PROJ = 0, M_KV = 1, M_WO = 3, M_FFN1 = 4, M_FFN2 = 5 };

#define GLL(src, dst) \
  __builtin_amdgcn_global_load_lds((const __attribute__((address_space(1))) unsigned int*)(src), \
                                   (__attribute__((address_space(3))) unsigned int*)(dst), 16, 0, 0)

template<int MODE>
__global__ __launch_bounds__(256) void mega(
    const u16* __restrict__ A, const u16* __restrict__ Bt,
    int M, int N, int K,
    u16* __restrict__ Ybf, float* __restrict__ Yf,
    const float* __restrict__ resf, const u16* __restrict__ resb,
    const float* __restrict__ bias,
    const u16* __restrict__ Kst, float* __restrict__ nsq,
    float* __restrict__ kvout)
{
  __shared__ u16 As[BM * BK];   // 8 KB
  __shared__ u16 Bs[BN * BK];   // 8 KB

  const int tid  = threadIdx.x;
  const int lane = tid & 63;
  const int w    = tid >> 6;
  const int wr = w >> 1, wc = w & 1;          // 2x2 wave grid, 64x64 per wave
  const int l15 = lane & 15, lg = lane >> 4;
  const long bm0 = (long)blockIdx.y * BM;
  const long bn0 = (long)blockIdx.x * BN;

  // staging: 512 chunks of 16B per operand tile; thread t does chunks t and t+256
  const int c0 = tid, c1 = tid + 256;
  const u16* aS0 = A  + (bm0 + (c0 >> 2)) * K + (c0 & 3) * 8;
  const u16* aS1 = A  + (bm0 + (c1 >> 2)) * K + (c1 & 3) * 8;
  const u16* bS0 = Bt + (bn0 + (c0 >> 2)) * K + (c0 & 3) * 8;
  const u16* bS1 = Bt + (bn0 + (c1 >> 2)) * K + (c1 & 3) * 8;
  u16* aD0 = As + w * 512;          // wave-uniform LDS bases (HW adds lane*16B)
  u16* aD1 = As + 2048 + w * 512;
  u16* bD0 = Bs + w * 512;
  u16* bD1 = Bs + 2048 + w * 512;

  f32x4 acc[4][4] = {};

  for (int k0 = 0; k0 < K; k0 += BK) {
    GLL(aS0 + k0, aD0);
    GLL(aS1 + k0, aD1);
    GLL(bS0 + k0, bD0);
    GLL(bS1 + k0, bD1);
    __syncthreads();   // drains vmcnt for staging, then barrier

    bf16x8 af[4], bfv[4];
#pragma unroll
    for (int m = 0; m < 4; ++m)
      af[m] = *(const bf16x8*)(As + (wr * 64 + m * 16 + l15) * BK + lg * 8);
#pragma unroll
    for (int n = 0; n < 4; ++n)
      bfv[n] = *(const bf16x8*)(Bs + (wc * 64 + n * 16 + l15) * BK + lg * 8);
#pragma unroll
    for (int m = 0; m < 4; ++m)
#pragma unroll
      for (int n = 0; n < 4; ++n)
        acc[m][n] = __builtin_amdgcn_mfma_f32_16x16x32_bf16(af[m], bfv[n], acc[m][n], 0, 0, 0);
    __syncthreads();   // LDS reads done before next stage overwrites
  }

  // C/D layout: col = lane&15, row = (lane>>4)*4 + r  [verified m89/m91]
  const int b = (int)(bm0 >> 12);   // row / Ss (block never spans batches)

  if constexpr (MODE == M_PROJ) {
    // store projection tile (bf16) + per-row sum-of-squares atomics
    float sk[16];
#pragma unroll
    for (int i = 0; i < 16; ++i) sk[i] = 0.f;
#pragma unroll
    for (int m = 0; m < 4; ++m) {
      const long row0 = bm0 + wr * 64 + m * 16 + lg * 4;
#pragma unroll
      for (int n = 0; n < 4; ++n) {
        const long col = bn0 + wc * 64 + n * 16 + l15;
#pragma unroll
        for (int r = 0; r < 4; ++r) {
          const float v = acc[m][n][r];
          Ybf[(row0 + r) * N + col] = f2bu(v);
          sk[m * 4 + r] += v * v;
        }
      }
    }
#pragma unroll
    for (int i = 0; i < 16; ++i) {
#pragma unroll
      for (int off = 1; off < 16; off <<= 1)
        sk[i] += __shfl_xor(sk[i], off, 64);
    }
    if (l15 == 0) {
#pragma unroll
      for (int m = 0; m < 4; ++m)
#pragma unroll
        for (int r = 0; r < 4; ++r)
          atomicAdd(&nsq[bm0 + wr * 64 + m * 16 + lg * 4 + r], sk[m * 4 + r]);
    }
  } else if constexpr (MODE == M_KV) {
    // acc = V tile; read stored K tile, scale rows by 1/||k||, reduce over rows
    float rnv[16];
#pragma unroll
    for (int m = 0; m < 4; ++m)
#pragma unroll
      for (int r = 0; r < 4; ++r) {
        const long row = bm0 + wr * 64 + m * 16 + lg * 4 + r;
        rnv[m * 4 + r] = 1.f / fmaxf(sqrtf(nsq[row]), 1e-12f);
      }
    float cs[4] = {0.f, 0.f, 0.f, 0.f};
#pragma unroll
    for (int m = 0; m < 4; ++m) {
      const long row0 = bm0 + wr * 64 + m * 16 + lg * 4;
#pragma unroll
      for (int n = 0; n < 4; ++n) {
        const long col = bn0 + wc * 64 + n * 16 + l15;
#pragma unroll
        for (int r = 0; r < 4; ++r)
          cs[n] += bfu(Kst[(row0 + r) * N + col]) * rnv[m * 4 + r] * acc[m][n][r];
      }
    }
#pragma unroll
    for (int n = 0; n < 4; ++n) {
      cs[n] += __shfl_xor(cs[n], 16, 64);
      cs[n] += __shfl_xor(cs[n], 32, 64);
    }
    if (lane < 16) {
#pragma unroll
      for (int n = 0; n < 4; ++n) {
        const long col = bn0 + wc * 64 + n * 16 + l15;
        atomicAdd(&kvout[(long)b * DIi + col], cs[n]);
      }
    }
  } else {
#pragma unroll
    for (int m = 0; m < 4; ++m) {
      const long row0 = bm0 + wr * 64 + m * 16 + lg * 4;
#pragma unroll
      for (int n = 0; n < 4; ++n) {
        const long col = bn0 + wc * 64 + n * 16 + l15;
#pragma unroll
        for (int r = 0; r < 4; ++r) {
          const long idx = (row0 + r) * N + col;
          const float v = acc[m][n][r];
          if constexpr (MODE == M_WO) {
            Ybf[idx] = f2bu(v + resf[idx]);
          } else if constexpr (MODE == M_FFN1) {
            float o = v + bias[col];
            o = o > 0.f ? o : 0.f;
            Ybf[idx] = f2bu(o);
          } else {  // M_FFN2
            Yf[idx] = v + bias[col] + bfu(resb[idx]);
          }
        }
      }
    }
  }
}

extern "C" void kernel_launch(void* const* d_in, const int* in_sizes, int n_in,
                              void* d_out, int out_size, void* d_ws, size_t ws_size,
                              hipStream_t stream) {
  const float* x  = (const float*)d_in[0];
  const float* wq = (const float*)d_in[1];
  const float* wk = (const float*)d_in[2];
  const float* wv = (const float*)d_in[3];
  const float* wo = (const float*)d_in[4];
  const float* w1 = (const float*)d_in[5];
  const float* b1 = (const float*)d_in[6];
  const float* w2 = (const float*)d_in[7];
  const float* b2 = (const float*)d_in[8];
  float* out = (float*)d_out;

  // workspace carve-up: ~180 MB peak
  char* p = (char*)d_ws;
  auto take = [&](size_t bytes) {
    char* r = p; p += (bytes + 255) & ~(size_t)255; return r;
  };
  u16*   xb   = (u16*)take((size_t)Mm * Dd * 2);    // x bf16; later reused as attn bf16
  u16*   wkT  = (u16*)take((size_t)DIi * Dd * 2);
  u16*   wqT  = (u16*)take((size_t)DIi * Dd * 2);
  u16*   wvT  = (u16*)take((size_t)DIi * Dd * 2);
  u16*   woT  = (u16*)take((size_t)Dd * DIi * 2);
  u16*   w1T  = (u16*)take((size_t)DIi * Dd * 2);
  u16*   w2T  = (u16*)take((size_t)Dd * DIi * 2);
  u16*   buf1 = (u16*)take((size_t)Mm * DIi * 2);   // K, then Q/Aprep, then h
  float* nksq = (float*)take((size_t)Mm * 4);
  float* nqsq = (float*)take((size_t)Mm * 4);
  float* kvp  = (float*)take((size_t)Bb * DIi * 4);
  (void)ws_size; (void)in_sizes; (void)n_in; (void)out_size;

  const dim3 tpB(32, 8);

  // per-call zeroing of atomic accumulators
  zero_f32<<<(Mm + 255) / 256, 256, 0, stream>>>(nksq, Mm);
  zero_f32<<<(Mm + 255) / 256, 256, 0, stream>>>(nqsq, Mm);
  zero_f32<<<(Bb * DIi + 255) / 256, 256, 0, stream>>>(kvp, Bb * DIi);

  // conversions
  f32_to_bf16_vec<<<2048, 256, 0, stream>>>(x, xb, (long)Mm * Dd / 4);
  transpose_f32_bf16<<<dim3(DIi / 32, Dd / 32), tpB, 0, stream>>>(wk, wkT, Dd, DIi);
  transpose_f32_bf16<<<dim3(DIi / 32, Dd / 32), tpB, 0, stream>>>(wq, wqT, Dd, DIi);
  transpose_f32_bf16<<<dim3(DIi / 32, Dd / 32), tpB, 0, stream>>>(wv, wvT, Dd, DIi);
  transpose_f32_bf16<<<dim3(Dd / 32, DIi / 32), tpB, 0, stream>>>(wo, woT, DIi, Dd);
  transpose_f32_bf16<<<dim3(DIi / 32, Dd / 32), tpB, 0, stream>>>(w1, w1T, Dd, DIi);
  transpose_f32_bf16<<<dim3(Dd / 32, DIi / 32), tpB, 0, stream>>>(w2, w2T, DIi, Dd);

  // K = x@wk -> buf1 (bf16) + nksq
  mega<M_PROJ><<<dim3(DIi / BN, Mm / BM), 256, 0, stream>>>(
      xb, wkT, Mm, DIi, Dd, buf1, nullptr, nullptr, nullptr, nullptr,
      nullptr, nksq, nullptr);

  // V tiles + fold 1/||k|| and reduce over rows -> kv[b,e]  (K dead after)
  mega<M_KV><<<dim3(DIi / BN, Mm / BM), 256, 0, stream>>>(
      xb, wvT, Mm, DIi, Dd, nullptr, nullptr, nullptr, nullptr, nullptr,
      buf1, nksq, kvp);

  // Q = x@wq -> buf1 (bf16) + nqsq
  mega<M_PROJ><<<dim3(DIi / BN, Mm / BM), 256, 0, stream>>>(
      xb, wqT, Mm, DIi, Dd, buf1, nullptr, nullptr, nullptr, nullptr,
      nullptr, nqsq, nullptr);

  // Aprep (in place on buf1): q * rsqrt(nqsq) * kv[b,e]
  prep_attn<<<4096, 256, 0, stream>>>(buf1, kvp, nqsq);

  // attn = Aprep @ wo + x -> bf16 into xb slot (xb dead)
  mega<M_WO><<<dim3(Dd / BN, Mm / BM), 256, 0, stream>>>(
      buf1, woT, Mm, Dd, DIi, xb, nullptr, x, nullptr, nullptr,
      nullptr, nullptr, nullptr);

  // h = relu(attn @ w1 + b1) -> buf1 (Aprep dead)
  mega<M_FFN1><<<dim3(DIi / BN, Mm / BM), 256, 0, stream>>>(
      xb, w1T, Mm, DIi, Dd, buf1, nullptr, nullptr, nullptr, b1,
      nullptr, nullptr, nullptr);

  // out = h @ w2 + b2 + attn
  mega<M_FFN2><<<dim3(Dd / BN, Mm / BM), 256, 0, stream>>>(
      buf1, w2T, Mm, Dd, DIi, nullptr, out, nullptr, xb, b2,
      nullptr, nullptr, nullptr);
}

// Round 4
// 653.898 us; speedup vs baseline: 1.5257x; 1.2215x over previous
//
#include <hip/hip_runtime.h>
#include <stdint.h>

// Problem constants
#define Bb  8
#define Ss  4096
#define Dd  512
#define DIi 2048
#define Mm  (Bb*Ss)   // 32768 rows

typedef unsigned short u16;
typedef __bf16 bf16x8 __attribute__((ext_vector_type(8)));
typedef float  f32x4  __attribute__((ext_vector_type(4)));

__device__ __forceinline__ float bfu(unsigned int u) {
  return __uint_as_float((u & 0xffffu) << 16);
}
__device__ __forceinline__ u16 f2bu(float f) {
  unsigned int x = __float_as_uint(f);
  return (u16)((x + 0x7fffu + ((x >> 16) & 1u)) >> 16);  // RNE
}

__global__ __launch_bounds__(256) void zero_f32(float* __restrict__ p, int n) {
  int i = blockIdx.x * 256 + threadIdx.x;
  if (i < n) p[i] = 0.f;
}

__global__ __launch_bounds__(256) void f32_to_bf16_vec(const float* __restrict__ in,
                                                       u16* __restrict__ outp, long n4) {
  long i = (long)blockIdx.x * 256 + threadIdx.x;
  const long st = (long)gridDim.x * 256;
  for (; i < n4; i += st) {
    float4 v = ((const float4*)in)[i];
    ushort4 o;
    o.x = f2bu(v.x); o.y = f2bu(v.y); o.z = f2bu(v.z); o.w = f2bu(v.w);
    ((ushort4*)outp)[i] = o;
  }
}

// transpose f32 [K][N] -> bf16 [N][K]
__global__ void transpose_f32_bf16(const float* __restrict__ W, u16* __restrict__ Wt,
                                   int K, int N) {
  __shared__ float t[32][33];
  const int n0 = blockIdx.x * 32, k0 = blockIdx.y * 32;
  const int tx = threadIdx.x, ty = threadIdx.y;  // 32 x 8
#pragma unroll
  for (int i = 0; i < 32; i += 8)
    t[ty + i][tx] = W[(long)(k0 + ty + i) * N + n0 + tx];
  __syncthreads();
#pragma unroll
  for (int i = 0; i < 32; i += 8)
    Wt[(long)(n0 + ty + i) * K + k0 + tx] = f2bu(t[tx][ty + i]);
}

// wob[b][n][k] = woT[n][k] * kv[b][k]   (bf16 out, 8 batch copies of wo^T)
__global__ __launch_bounds__(256) void build_wob(const u16* __restrict__ woT,
                                                 const float* __restrict__ kv,
                                                 u16* __restrict__ wob) {
  const int b = blockIdx.y;
  long i = (long)blockIdx.x * 256 + threadIdx.x;            // i indexes 8-elem groups
  const long tot = (long)Dd * DIi / 8;
  if (i >= tot) return;
  const long e = i * 8;
  const int k = (int)(e & (DIi - 1));
  ushort4 w0 = *(const ushort4*)(woT + e);
  ushort4 w1 = *(const ushort4*)(woT + e + 4);
  const float* kvp = kv + (long)b * DIi + k;
  ushort4 o0, o1;
  o0.x = f2bu(bfu(w0.x) * kvp[0]); o0.y = f2bu(bfu(w0.y) * kvp[1]);
  o0.z = f2bu(bfu(w0.z) * kvp[2]); o0.w = f2bu(bfu(w0.w) * kvp[3]);
  o1.x = f2bu(bfu(w1.x) * kvp[4]); o1.y = f2bu(bfu(w1.y) * kvp[5]);
  o1.z = f2bu(bfu(w1.z) * kvp[6]); o1.w = f2bu(bfu(w1.w) * kvp[7]);
  u16* dst = wob + (long)b * Dd * DIi + e;
  *(ushort4*)dst = o0;
  *(ushort4*)(dst + 4) = o1;
}

#define GLL(src, dst) \
  __builtin_amdgcn_global_load_lds((const __attribute__((address_space(1))) unsigned int*)(src), \
                                   (__attribute__((address_space(3))) unsigned int*)(dst), 16, 0, 0)

// =================== 256^2-tile 8-wave pipelined GEMM ===================
// C[M,N] = A[M,K] @ Bt[N,K]^T. BM=BN=256, BK=64, 512 threads (8 waves 2x4),
// LDS 128 KB: 2 buffers x (A 32KB + B 32KB). Counted vmcnt at tile
// boundaries only; 4 phases per K-tile; setprio around MFMA clusters.
// LDS layout per 128x64 half-tile: byte = (row>>3)*1024 + (col>>3)*128
//   + (row&7)*16 + (col&7)*2  -> staged with per-lane permuted global source
//   (linear LDS dest), ds_read_b128 bank-clean by construction.
enum { G_PROJ = 0, G_WO = 1, G_FFN1 = 2, G_FFN2 = 3 };

template<int MODE>
__global__ __launch_bounds__(512, 2) void gemm8(
    const u16* __restrict__ A, const u16* __restrict__ Bt,
    int N, int K,
    u16* __restrict__ Ybf, float* __restrict__ Yf,
    const float* __restrict__ resf, const u16* __restrict__ resb,
    const float* __restrict__ bias,
    float* __restrict__ nsq, const float* __restrict__ nsqIn)
{
  __shared__ u16 lds8[65536];   // 128 KB

  const int tid  = threadIdx.x;
  const int lane = tid & 63;
  const int wid  = tid >> 6;                 // 0..7
  const int wr = wid >> 2, wc = wid & 3;     // 2 x 4 wave grid; wave tile 128x64
  const int l15 = lane & 15, lg = lane >> 4;
  const long bm0 = (long)blockIdx.y * 256;
  const long bn0 = (long)blockIdx.x * 256;
  const int NT = K >> 6;                     // K-tiles of 64

  const int bq = (int)(bm0 >> 12);           // batch of this row-block
  const u16* pA = A + bm0 * K;
  const u16* pB = Bt + bn0 * K + (MODE == G_WO ? (size_t)bq * Dd * DIi : 0);

  // staging decode (per thread): chunk = j*512 + tid
  const int rowT = ((tid >> 6) << 3) | (tid & 7);   // 0..63 (j=0); +64 for j=1
  const int cc8  = ((tid >> 3) & 7) * 8;            // col chunk * 8

  // STAGE one 128x64 half-tile (2 x global_load_lds dwordx4 per thread)
#define STAGE(PTR, LD, H, TT, BUFU, REGU) do {                                  \
    const u16* s0_ = (PTR) + (size_t)((H) * 128 + rowT) * (LD)                  \
                     + (size_t)(TT) * 64 + cc8;                                 \
    u16* d_ = lds8 + (BUFU) + (REGU) + (H) * 8192 + wid * 512;                  \
    GLL(s0_, d_);                                                               \
    GLL(s0_ + (size_t)64 * (LD), d_ + 4096);                                    \
  } while (0)

  // frag-read base offsets (u16 units)
  const int aoff = (wr * 16384 + (l15 >> 3) * 1024 + lg * 128 + (l15 & 7) * 16) >> 1;
  const int boff = (32768 + (wc >> 1) * 16384 + (wc & 1) * 8192 +
                    (l15 >> 3) * 1024 + lg * 128 + (l15 & 7) * 16) >> 1;
#define LDA(M_, KS_, BU_) (*(const bf16x8*)(lds8 + (BU_) + aoff + (M_) * 1024 + (KS_) * 256))
#define LDB(N_, KS_, BU_) (*(const bf16x8*)(lds8 + (BU_) + boff + (N_) * 1024 + (KS_) * 256))

  f32x4 acc[8][4] = {};

  // ---- prologue: tile 0 (4 halves) + tile 1 A-half0 ----
  STAGE(pA, K, 0, 0, 0, 0);
  STAGE(pA, K, 1, 0, 0, 0);
  STAGE(pB, K, 0, 0, 0, 16384);
  STAGE(pB, K, 1, 0, 0, 16384);
  STAGE(pA, K, 0, 1, 32768, 0);
  asm volatile("s_waitcnt vmcnt(2)" ::: "memory");
  __builtin_amdgcn_s_barrier();

  for (int t = 0; t < NT; ++t) {
    const int bufu = (t & 1) * 32768;
    const int nbuf = bufu ^ 32768;
    bf16x8 aF[4], bF[4];

    // ---- phase 0: B ks0 + A(m0-3) ks0 ; stage H[t+1, A half1] ----
#pragma unroll
    for (int n = 0; n < 4; ++n) bF[n] = LDB(n, 0, bufu);
#pragma unroll
    for (int m = 0; m < 4; ++m) aF[m] = LDA(m, 0, bufu);
    if (t + 1 < NT) STAGE(pA, K, 1, t + 1, nbuf, 0);
    __builtin_amdgcn_s_barrier();
    __builtin_amdgcn_s_setprio(1);
#pragma unroll
    for (int m = 0; m < 4; ++m)
#pragma unroll
      for (int n = 0; n < 4; ++n)
        acc[m][n] = __builtin_amdgcn_mfma_f32_16x16x32_bf16(aF[m], bF[n], acc[m][n], 0, 0, 0);
    __builtin_amdgcn_s_setprio(0);

    // ---- phase 1: A(m4-7) ks0 ; stage H[t+1, B half0] ----
#pragma unroll
    for (int m = 0; m < 4; ++m) aF[m] = LDA(4 + m, 0, bufu);
    if (t + 1 < NT) STAGE(pB, K, 0, t + 1, nbuf, 16384);
    __builtin_amdgcn_s_barrier();
    __builtin_amdgcn_s_setprio(1);
#pragma unroll
    for (int m = 0; m < 4; ++m)
#pragma unroll
      for (int n = 0; n < 4; ++n)
        acc[4 + m][n] = __builtin_amdgcn_mfma_f32_16x16x32_bf16(aF[m], bF[n], acc[4 + m][n], 0, 0, 0);
    __builtin_amdgcn_s_setprio(0);

    // ---- phase 2: B ks1 + A(m0-3) ks1 ; stage H[t+1, B half1] ----
#pragma unroll
    for (int n = 0; n < 4; ++n) bF[n] = LDB(n, 1, bufu);
#pragma unroll
    for (int m = 0; m < 4; ++m) aF[m] = LDA(m, 1, bufu);
    if (t + 1 < NT) STAGE(pB, K, 1, t + 1, nbuf, 16384);
    __builtin_amdgcn_s_barrier();
    __builtin_amdgcn_s_setprio(1);
#pragma unroll
    for (int m = 0; m < 4; ++m)
#pragma unroll
      for (int n = 0; n < 4; ++n)
        acc[m][n] = __builtin_amdgcn_mfma_f32_16x16x32_bf16(aF[m], bF[n], acc[m][n], 0, 0, 0);
    __builtin_amdgcn_s_setprio(0);

    // ---- phase 3: A(m4-7) ks1 ----
#pragma unroll
    for (int m = 0; m < 4; ++m) aF[m] = LDA(4 + m, 1, bufu);
    __builtin_amdgcn_s_barrier();
    __builtin_amdgcn_s_setprio(1);
#pragma unroll
    for (int m = 0; m < 4; ++m)
#pragma unroll
      for (int n = 0; n < 4; ++n)
        acc[4 + m][n] = __builtin_amdgcn_mfma_f32_16x16x32_bf16(aF[m], bF[n], acc[4 + m][n], 0, 0, 0);
    __builtin_amdgcn_s_setprio(0);

    // ---- tile boundary ----
    if (t + 1 < NT) {
      __builtin_amdgcn_s_barrier();            // all reads of buf cur complete
      if (t + 2 < NT) {
        STAGE(pA, K, 0, t + 2, bufu, 0);       // reuse just-freed A-half0 slot
        asm volatile("s_waitcnt vmcnt(2)" ::: "memory");
      } else {
        asm volatile("s_waitcnt vmcnt(0)" ::: "memory");
      }
      __builtin_amdgcn_s_barrier();            // tile t+1 buffer visible to all
    }
  }

  // =================== epilogue ===================
  if constexpr (MODE == G_PROJ) {
    float sk[32];
#pragma unroll
    for (int i = 0; i < 32; ++i) sk[i] = 0.f;
#pragma unroll
    for (int m = 0; m < 8; ++m) {
      const long row0 = bm0 + wr * 128 + m * 16 + lg * 4;
#pragma unroll
      for (int n = 0; n < 4; ++n) {
        const long col = bn0 + wc * 64 + n * 16 + l15;
#pragma unroll
        for (int r = 0; r < 4; ++r) {
          const float v = acc[m][n][r];
          Ybf[(row0 + r) * N + col] = f2bu(v);
          sk[m * 4 + r] += v * v;
        }
      }
    }
#pragma unroll
    for (int i = 0; i < 32; ++i) {
#pragma unroll
      for (int off = 1; off < 16; off <<= 1)
        sk[i] += __shfl_xor(sk[i], off, 64);
    }
    if (l15 == 0) {
#pragma unroll
      for (int m = 0; m < 8; ++m)
#pragma unroll
        for (int r = 0; r < 4; ++r)
          atomicAdd(&nsq[bm0 + wr * 128 + m * 16 + lg * 4 + r], sk[m * 4 + r]);
    }
  } else {
#pragma unroll
    for (int m = 0; m < 8; ++m) {
      const long row0 = bm0 + wr * 128 + m * 16 + lg * 4;
      float rq[4];
      if constexpr (MODE == G_WO) {
#pragma unroll
        for (int r = 0; r < 4; ++r)
          rq[r] = 1.f / fmaxf(sqrtf(nsqIn[row0 + r]), 1e-12f);
      }
#pragma unroll
      for (int n = 0; n < 4; ++n) {
        const long col = bn0 + wc * 64 + n * 16 + l15;
#pragma unroll
        for (int r = 0; r < 4; ++r) {
          const long idx = (row0 + r) * N + col;
          const float v = acc[m][n][r];
          if constexpr (MODE == G_WO) {
            Ybf[idx] = f2bu(v * rq[r] + resf[idx]);
          } else if constexpr (MODE == G_FFN1) {
            float o = v + bias[col];
            o = o > 0.f ? o : 0.f;
            Ybf[idx] = f2bu(o);
          } else {  // G_FFN2
            Yf[idx] = v + bias[col] + bfu(resb[idx]);
          }
        }
      }
    }
  }
#undef STAGE
#undef LDA
#undef LDB
}

// ============ round-3 proven 128^2 kernel, KV mode only ============
#define BM 128
#define BN 128
#define BK 32
__global__ __launch_bounds__(256) void mega_kv(
    const u16* __restrict__ A, const u16* __restrict__ Bt,
    int M, int N, int K,
    const u16* __restrict__ Kst, const float* __restrict__ nsq,
    float* __restrict__ kvout)
{
  __shared__ u16 As[BM * BK];
  __shared__ u16 Bs[BN * BK];

  const int tid  = threadIdx.x;
  const int lane = tid & 63;
  const int w    = tid >> 6;
  const int wr = w >> 1, wc = w & 1;
  const int l15 = lane & 15, lg = lane >> 4;
  const long bm0 = (long)blockIdx.y * BM;
  const long bn0 = (long)blockIdx.x * BN;

  const int c0 = tid, c1 = tid + 256;
  const u16* aS0 = A  + (bm0 + (c0 >> 2)) * K + (c0 & 3) * 8;
  const u16* aS1 = A  + (bm0 + (c1 >> 2)) * K + (c1 & 3) * 8;
  const u16* bS0 = Bt + (bn0 + (c0 >> 2)) * K + (c0 & 3) * 8;
  const u16* bS1 = Bt + (bn0 + (c1 >> 2)) * K + (c1 & 3) * 8;
  u16* aD0 = As + w * 512;
  u16* aD1 = As + 2048 + w * 512;
  u16* bD0 = Bs + w * 512;
  u16* bD1 = Bs + 2048 + w * 512;

  f32x4 acc[4][4] = {};

  for (int k0 = 0; k0 < K; k0 += BK) {
    GLL(aS0 + k0, aD0);
    GLL(aS1 + k0, aD1);
    GLL(bS0 + k0, bD0);
    GLL(bS1 + k0, bD1);
    __syncthreads();

    bf16x8 af[4], bfv[4];
#pragma unroll
    for (int m = 0; m < 4; ++m)
      af[m] = *(const bf16x8*)(As + (wr * 64 + m * 16 + l15) * BK + lg * 8);
#pragma unroll
    for (int n = 0; n < 4; ++n)
      bfv[n] = *(const bf16x8*)(Bs + (wc * 64 + n * 16 + l15) * BK + lg * 8);
#pragma unroll
    for (int m = 0; m < 4; ++m)
#pragma unroll
      for (int n = 0; n < 4; ++n)
        acc[m][n] = __builtin_amdgcn_mfma_f32_16x16x32_bf16(af[m], bfv[n], acc[m][n], 0, 0, 0);
    __syncthreads();
  }

  const int b = (int)(bm0 >> 12);
  float rnv[16];
#pragma unroll
  for (int m = 0; m < 4; ++m)
#pragma unroll
    for (int r = 0; r < 4; ++r) {
      const long row = bm0 + wr * 64 + m * 16 + lg * 4 + r;
      rnv[m * 4 + r] = 1.f / fmaxf(sqrtf(nsq[row]), 1e-12f);
    }
  float cs[4] = {0.f, 0.f, 0.f, 0.f};
#pragma unroll
  for (int m = 0; m < 4; ++m) {
    const long row0 = bm0 + wr * 64 + m * 16 + lg * 4;
#pragma unroll
    for (int n = 0; n < 4; ++n) {
      const long col = bn0 + wc * 64 + n * 16 + l15;
#pragma unroll
      for (int r = 0; r < 4; ++r)
        cs[n] += bfu(Kst[(row0 + r) * N + col]) * rnv[m * 4 + r] * acc[m][n][r];
    }
  }
#pragma unroll
  for (int n = 0; n < 4; ++n) {
    cs[n] += __shfl_xor(cs[n], 16, 64);
    cs[n] += __shfl_xor(cs[n], 32, 64);
  }
  if (lane < 16) {
#pragma unroll
    for (int n = 0; n < 4; ++n) {
      const long col = bn0 + wc * 64 + n * 16 + l15;
      atomicAdd(&kvout[(long)b * DIi + col], cs[n]);
    }
  }
}

extern "C" void kernel_launch(void* const* d_in, const int* in_sizes, int n_in,
                              void* d_out, int out_size, void* d_ws, size_t ws_size,
                              hipStream_t stream) {
  const float* x  = (const float*)d_in[0];
  const float* wq = (const float*)d_in[1];
  const float* wk = (const float*)d_in[2];
  const float* wv = (const float*)d_in[3];
  const float* wo = (const float*)d_in[4];
  const float* w1 = (const float*)d_in[5];
  const float* b1 = (const float*)d_in[6];
  const float* w2 = (const float*)d_in[7];
  const float* b2 = (const float*)d_in[8];
  float* out = (float*)d_out;

  // workspace carve-up: ~197 MB peak
  char* p = (char*)d_ws;
  auto take = [&](size_t bytes) {
    char* r = p; p += (bytes + 255) & ~(size_t)255; return r;
  };
  u16*   xb   = (u16*)take((size_t)Mm * Dd * 2);    // x bf16; later attn bf16
  u16*   wkT  = (u16*)take((size_t)DIi * Dd * 2);
  u16*   wqT  = (u16*)take((size_t)DIi * Dd * 2);
  u16*   wvT  = (u16*)take((size_t)DIi * Dd * 2);
  u16*   woT  = (u16*)take((size_t)Dd * DIi * 2);
  u16*   w1T  = (u16*)take((size_t)DIi * Dd * 2);
  u16*   w2T  = (u16*)take((size_t)Dd * DIi * 2);
  u16*   wob  = (u16*)take((size_t)Bb * Dd * DIi * 2);  // 16.8 MB
  u16*   buf1 = (u16*)take((size_t)Mm * DIi * 2);   // K, then Q, then h
  float* nksq = (float*)take((size_t)Mm * 4);
  float* nqsq = (float*)take((size_t)Mm * 4);
  float* kvp  = (float*)take((size_t)Bb * DIi * 4);
  (void)ws_size; (void)in_sizes; (void)n_in; (void)out_size;

  const dim3 tpB(32, 8);

  zero_f32<<<(Mm + 255) / 256, 256, 0, stream>>>(nksq, Mm);
  zero_f32<<<(Mm + 255) / 256, 256, 0, stream>>>(nqsq, Mm);
  zero_f32<<<(Bb * DIi + 255) / 256, 256, 0, stream>>>(kvp, Bb * DIi);

  f32_to_bf16_vec<<<2048, 256, 0, stream>>>(x, xb, (long)Mm * Dd / 4);
  transpose_f32_bf16<<<dim3(DIi / 32, Dd / 32), tpB, 0, stream>>>(wk, wkT, Dd, DIi);
  transpose_f32_bf16<<<dim3(DIi / 32, Dd / 32), tpB, 0, stream>>>(wq, wqT, Dd, DIi);
  transpose_f32_bf16<<<dim3(DIi / 32, Dd / 32), tpB, 0, stream>>>(wv, wvT, Dd, DIi);
  transpose_f32_bf16<<<dim3(Dd / 32, DIi / 32), tpB, 0, stream>>>(wo, woT, DIi, Dd);
  transpose_f32_bf16<<<dim3(DIi / 32, Dd / 32), tpB, 0, stream>>>(w1, w1T, Dd, DIi);
  transpose_f32_bf16<<<dim3(Dd / 32, DIi / 32), tpB, 0, stream>>>(w2, w2T, DIi, Dd);

  // K = x@wk -> buf1 (bf16) + nksq
  gemm8<G_PROJ><<<dim3(DIi / 256, Mm / 256), 512, 0, stream>>>(
      xb, wkT, DIi, Dd, buf1, nullptr, nullptr, nullptr, nullptr, nksq, nullptr);

  // kv[b,e] via V tiles + stored K + nksq  (K dead after)
  mega_kv<<<dim3(DIi / BN, Mm / BM), 256, 0, stream>>>(
      xb, wvT, Mm, DIi, Dd, buf1, nksq, kvp);

  // Q = x@wq -> buf1 (bf16) + nqsq
  gemm8<G_PROJ><<<dim3(DIi / 256, Mm / 256), 512, 0, stream>>>(
      xb, wqT, DIi, Dd, buf1, nullptr, nullptr, nullptr, nullptr, nqsq, nullptr);

  // wob[b] = woT * kv[b]
  build_wob<<<dim3((Dd * DIi / 8 + 255) / 256, Bb), 256, 0, stream>>>(woT, kvp, wob);

  // attn = (q @ wob[b]) * rsqrt(nqsq) + x -> bf16 into xb slot
  gemm8<G_WO><<<dim3(Dd / 256, Mm / 256), 512, 0, stream>>>(
      buf1, wob, Dd, DIi, xb, nullptr, x, nullptr, nullptr, nullptr, nqsq);

  // h = relu(attn @ w1 + b1) -> buf1
  gemm8<G_FFN1><<<dim3(DIi / 256, Mm / 256), 512, 0, stream>>>(
      xb, w1T, DIi, Dd, buf1, nullptr, nullptr, nullptr, b1, nullptr, nullptr);

  // out = h @ w2 + b2 + attn
  gemm8<G_FFN2><<<dim3(Dd / 256, Mm / 256), 512, 0, stream>>>(
      buf1, w2T, Dd, DIi, nullptr, out, nullptr, xb, b2, nullptr, nullptr);
}

// Round 5
// 621.750 us; speedup vs baseline: 1.6046x; 1.0517x over previous
//
#include <hip/hip_runtime.h>
#include <stdint.h>

// Problem constants
#define Bb  8
#define Ss  4096
#define Dd  512
#define DIi 2048
#define Mm  (Bb*Ss)   // 32768 rows

typedef unsigned short u16;
typedef __bf16 bf16x8 __attribute__((ext_vector_type(8)));
typedef float  f32x4  __attribute__((ext_vector_type(4)));

__device__ __forceinline__ float bfu(unsigned int u) {
  return __uint_as_float((u & 0xffffu) << 16);
}
__device__ __forceinline__ u16 f2bu(float f) {
  unsigned int x = __float_as_uint(f);
  return (u16)((x + 0x7fffu + ((x >> 16) & 1u)) >> 16);  // RNE
}

__global__ __launch_bounds__(256) void zero_f32(float* __restrict__ p, int n) {
  int i = blockIdx.x * 256 + threadIdx.x;
  if (i < n) p[i] = 0.f;
}

__global__ __launch_bounds__(256) void f32_to_bf16_vec(const float* __restrict__ in,
                                                       u16* __restrict__ outp, long n4) {
  long i = (long)blockIdx.x * 256 + threadIdx.x;
  const long st = (long)gridDim.x * 256;
  for (; i < n4; i += st) {
    float4 v = ((const float4*)in)[i];
    ushort4 o;
    o.x = f2bu(v.x); o.y = f2bu(v.y); o.z = f2bu(v.z); o.w = f2bu(v.w);
    ((ushort4*)outp)[i] = o;
  }
}

// batched transpose f32 [K][N] -> bf16 [N][K]; blockIdx.z selects the pair
__global__ void transpose_f32_bf16_z(const float* s0, const float* s1,
                                     const float* s2, const float* s3,
                                     u16* d0, u16* d1, u16* d2, u16* d3,
                                     int K, int N) {
  const float* W; u16* Wt;
  switch (blockIdx.z) {
    case 0:  W = s0; Wt = d0; break;
    case 1:  W = s1; Wt = d1; break;
    case 2:  W = s2; Wt = d2; break;
    default: W = s3; Wt = d3; break;
  }
  __shared__ float t[32][33];
  const int n0 = blockIdx.x * 32, k0 = blockIdx.y * 32;
  const int tx = threadIdx.x, ty = threadIdx.y;  // 32 x 8
#pragma unroll
  for (int i = 0; i < 32; i += 8)
    t[ty + i][tx] = W[(long)(k0 + ty + i) * N + n0 + tx];
  __syncthreads();
#pragma unroll
  for (int i = 0; i < 32; i += 8)
    Wt[(long)(n0 + ty + i) * K + k0 + tx] = f2bu(t[tx][ty + i]);
}

// wob[b][n][k] = woT[n][k] * kv[b][k]   (bf16 out, 8 batch copies of wo^T)
__global__ __launch_bounds__(256) void build_wob(const u16* __restrict__ woT,
                                                 const float* __restrict__ kv,
                                                 u16* __restrict__ wob) {
  const int b = blockIdx.y;
  long i = (long)blockIdx.x * 256 + threadIdx.x;            // i indexes 8-elem groups
  const long tot = (long)Dd * DIi / 8;
  if (i >= tot) return;
  const long e = i * 8;
  const int k = (int)(e & (DIi - 1));
  ushort4 w0 = *(const ushort4*)(woT + e);
  ushort4 w1 = *(const ushort4*)(woT + e + 4);
  const float* kvp = kv + (long)b * DIi + k;
  ushort4 o0, o1;
  o0.x = f2bu(bfu(w0.x) * kvp[0]); o0.y = f2bu(bfu(w0.y) * kvp[1]);
  o0.z = f2bu(bfu(w0.z) * kvp[2]); o0.w = f2bu(bfu(w0.w) * kvp[3]);
  o1.x = f2bu(bfu(w1.x) * kvp[4]); o1.y = f2bu(bfu(w1.y) * kvp[5]);
  o1.z = f2bu(bfu(w1.z) * kvp[6]); o1.w = f2bu(bfu(w1.w) * kvp[7]);
  u16* dst = wob + (long)b * Dd * DIi + e;
  *(ushort4*)dst = o0;
  *(ushort4*)(dst + 4) = o1;
}

#define GLL(src, dst) \
  __builtin_amdgcn_global_load_lds((const __attribute__((address_space(1))) unsigned int*)(src), \
                                   (__attribute__((address_space(3))) unsigned int*)(dst), 16, 0, 0)

// =================== 256^2-tile 8-wave pipelined GEMM ===================
// C[M,N] = A[M,K] @ Bt[N,K]^T. BM=BN=256, BK=64, 512 threads (8 waves 2x4),
// LDS 128 KB: 2 buffers x (A 32KB + B 32KB). Counted vmcnt at tile
// boundaries only; 4 phases per K-tile; setprio around MFMA clusters.
// G_KV: after main loop (acc = V tile), re-stage the 256x256 stored-K tile
// into the (now free) 128 KB LDS with XOR-swizzle (both-sides, rule #21),
// fold 1/||k||, reduce over rows -> atomicAdd kv[b,col]. No C store.
enum { G_PROJ = 0, G_WO = 1, G_FFN1 = 2, G_FFN2 = 3, G_KV = 4 };

template<int MODE>
__global__ __launch_bounds__(512, 2) void gemm8(
    const u16* __restrict__ A, const u16* __restrict__ Bt,
    int N, int K,
    u16* __restrict__ Ybf, float* __restrict__ Yf,
    const float* __restrict__ resf, const u16* __restrict__ resb,
    const float* __restrict__ bias,
    float* __restrict__ nsq, const float* __restrict__ nsqIn,
    const u16* __restrict__ Kst, float* __restrict__ kvout)
{
  __shared__ u16 lds8[65536];   // 128 KB

  const int tid  = threadIdx.x;
  const int lane = tid & 63;
  const int wid  = tid >> 6;                 // 0..7
  const int wr = wid >> 2, wc = wid & 3;     // 2 x 4 wave grid; wave tile 128x64
  const int l15 = lane & 15, lg = lane >> 4;
  const long bm0 = (long)blockIdx.y * 256;
  const long bn0 = (long)blockIdx.x * 256;
  const int NT = K >> 6;                     // K-tiles of 64

  const int bq = (int)(bm0 >> 12);           // batch of this row-block
  const u16* pA = A + bm0 * K;
  const u16* pB = Bt + bn0 * K + (MODE == G_WO ? (size_t)bq * Dd * DIi : 0);

  // staging decode (per thread): chunk = j*512 + tid
  const int rowT = ((tid >> 6) << 3) | (tid & 7);   // 0..63 (j=0); +64 for j=1
  const int cc8  = ((tid >> 3) & 7) * 8;            // col chunk * 8

  // STAGE one 128x64 half-tile (2 x global_load_lds dwordx4 per thread)
#define STAGE(PTR, LD, H, TT, BUFU, REGU) do {                                  \
    const u16* s0_ = (PTR) + (size_t)((H) * 128 + rowT) * (LD)                  \
                     + (size_t)(TT) * 64 + cc8;                                 \
    u16* d_ = lds8 + (BUFU) + (REGU) + (H) * 8192 + wid * 512;                  \
    GLL(s0_, d_);                                                               \
    GLL(s0_ + (size_t)64 * (LD), d_ + 4096);                                    \
  } while (0)

  // frag-read base offsets (u16 units)
  const int aoff = (wr * 16384 + (l15 >> 3) * 1024 + lg * 128 + (l15 & 7) * 16) >> 1;
  const int boff = (32768 + (wc >> 1) * 16384 + (wc & 1) * 8192 +
                    (l15 >> 3) * 1024 + lg * 128 + (l15 & 7) * 16) >> 1;
#define LDA(M_, KS_, BU_) (*(const bf16x8*)(lds8 + (BU_) + aoff + (M_) * 1024 + (KS_) * 256))
#define LDB(N_, KS_, BU_) (*(const bf16x8*)(lds8 + (BU_) + boff + (N_) * 1024 + (KS_) * 256))

  f32x4 acc[8][4] = {};

  // ---- prologue: tile 0 (4 halves) + tile 1 A-half0 ----
  STAGE(pA, K, 0, 0, 0, 0);
  STAGE(pA, K, 1, 0, 0, 0);
  STAGE(pB, K, 0, 0, 0, 16384);
  STAGE(pB, K, 1, 0, 0, 16384);
  STAGE(pA, K, 0, 1, 32768, 0);
  asm volatile("s_waitcnt vmcnt(2)" ::: "memory");
  __builtin_amdgcn_s_barrier();

  for (int t = 0; t < NT; ++t) {
    const int bufu = (t & 1) * 32768;
    const int nbuf = bufu ^ 32768;
    bf16x8 aF[4], bF[4];

    // ---- phase 0: B ks0 + A(m0-3) ks0 ; stage H[t+1, A half1] ----
#pragma unroll
    for (int n = 0; n < 4; ++n) bF[n] = LDB(n, 0, bufu);
#pragma unroll
    for (int m = 0; m < 4; ++m) aF[m] = LDA(m, 0, bufu);
    if (t + 1 < NT) STAGE(pA, K, 1, t + 1, nbuf, 0);
    __builtin_amdgcn_s_barrier();
    __builtin_amdgcn_s_setprio(1);
#pragma unroll
    for (int m = 0; m < 4; ++m)
#pragma unroll
      for (int n = 0; n < 4; ++n)
        acc[m][n] = __builtin_amdgcn_mfma_f32_16x16x32_bf16(aF[m], bF[n], acc[m][n], 0, 0, 0);
    __builtin_amdgcn_s_setprio(0);

    // ---- phase 1: A(m4-7) ks0 ; stage H[t+1, B half0] ----
#pragma unroll
    for (int m = 0; m < 4; ++m) aF[m] = LDA(4 + m, 0, bufu);
    if (t + 1 < NT) STAGE(pB, K, 0, t + 1, nbuf, 16384);
    __builtin_amdgcn_s_barrier();
    __builtin_amdgcn_s_setprio(1);
#pragma unroll
    for (int m = 0; m < 4; ++m)
#pragma unroll
      for (int n = 0; n < 4; ++n)
        acc[4 + m][n] = __builtin_amdgcn_mfma_f32_16x16x32_bf16(aF[m], bF[n], acc[4 + m][n], 0, 0, 0);
    __builtin_amdgcn_s_setprio(0);

    // ---- phase 2: B ks1 + A(m0-3) ks1 ; stage H[t+1, B half1] ----
#pragma unroll
    for (int n = 0; n < 4; ++n) bF[n] = LDB(n, 1, bufu);
#pragma unroll
    for (int m = 0; m < 4; ++m) aF[m] = LDA(m, 1, bufu);
    if (t + 1 < NT) STAGE(pB, K, 1, t + 1, nbuf, 16384);
    __builtin_amdgcn_s_barrier();
    __builtin_amdgcn_s_setprio(1);
#pragma unroll
    for (int m = 0; m < 4; ++m)
#pragma unroll
      for (int n = 0; n < 4; ++n)
        acc[m][n] = __builtin_amdgcn_mfma_f32_16x16x32_bf16(aF[m], bF[n], acc[m][n], 0, 0, 0);
    __builtin_amdgcn_s_setprio(0);

    // ---- phase 3: A(m4-7) ks1 ----
#pragma unroll
    for (int m = 0; m < 4; ++m) aF[m] = LDA(4 + m, 1, bufu);
    __builtin_amdgcn_s_barrier();
    __builtin_amdgcn_s_setprio(1);
#pragma unroll
    for (int m = 0; m < 4; ++m)
#pragma unroll
      for (int n = 0; n < 4; ++n)
        acc[4 + m][n] = __builtin_amdgcn_mfma_f32_16x16x32_bf16(aF[m], bF[n], acc[4 + m][n], 0, 0, 0);
    __builtin_amdgcn_s_setprio(0);

    // ---- tile boundary ----
    if (t + 1 < NT) {
      __builtin_amdgcn_s_barrier();            // all reads of buf cur complete
      if (t + 2 < NT) {
        STAGE(pA, K, 0, t + 2, bufu, 0);       // reuse just-freed A-half0 slot
        asm volatile("s_waitcnt vmcnt(2)" ::: "memory");
      } else {
        asm volatile("s_waitcnt vmcnt(0)" ::: "memory");
      }
      __builtin_amdgcn_s_barrier();            // tile t+1 buffer visible to all
    }
  }

  // =================== epilogue ===================
  if constexpr (MODE == G_KV) {
    // acc = V tile. Re-stage the 256x256 K-tile into lds8 (128 KB exactly),
    // XOR-swizzled: 16B slot s in row r holds col-chunk (s ^ (r&15)).
    __syncthreads();                       // all LDS frag reads done
#pragma unroll
    for (int i = 0; i < 16; ++i) {
      const int r_ = i * 16 + wid * 2 + (lane >> 5);     // tile row 0..255
      const int c_ = (lane & 31) ^ (r_ & 15);            // swizzled 16B chunk
      const u16* src = Kst + (size_t)(bm0 + r_) * N + bn0 + c_ * 8;
      u16* d_ = lds8 + i * 4096 + wid * 512;             // +lane*16B by HW
      GLL(src, d_);
    }
    asm volatile("s_waitcnt vmcnt(0)" ::: "memory");
    __builtin_amdgcn_s_barrier();

    const int col4 = wc * 64 + l15;        // + n*16 below
    float cs[4] = {0.f, 0.f, 0.f, 0.f};
#pragma unroll
    for (int m = 0; m < 8; ++m) {
      const long row0g = bm0 + wr * 128 + m * 16 + lg * 4;
      float rn4[4];
#pragma unroll
      for (int r = 0; r < 4; ++r)
        rn4[r] = 1.f / fmaxf(sqrtf(nsqIn[row0g + r]), 1e-12f);
#pragma unroll
      for (int n = 0; n < 4; ++n) {
        const int col = col4 + n * 16;
#pragma unroll
        for (int r = 0; r < 4; ++r) {
          const int krow = wr * 128 + m * 16 + lg * 4 + r;
          const int byte_ = krow * 512 + (((col >> 3) ^ (krow & 15)) << 4) + (col & 7) * 2;
          const float kvl = bfu(*(const u16*)((const char*)lds8 + byte_));
          cs[n] += kvl * rn4[r] * acc[m][n][r];
        }
      }
    }
#pragma unroll
    for (int n = 0; n < 4; ++n) {
      cs[n] += __shfl_xor(cs[n], 16, 64);
      cs[n] += __shfl_xor(cs[n], 32, 64);
    }
    if (lane < 16) {
#pragma unroll
      for (int n = 0; n < 4; ++n) {
        const long col = bn0 + wc * 64 + n * 16 + l15;
        atomicAdd(&kvout[(long)bq * DIi + col], cs[n]);
      }
    }
  } else if constexpr (MODE == G_PROJ) {
    float sk[32];
#pragma unroll
    for (int i = 0; i < 32; ++i) sk[i] = 0.f;
#pragma unroll
    for (int m = 0; m < 8; ++m) {
      const long row0 = bm0 + wr * 128 + m * 16 + lg * 4;
#pragma unroll
      for (int n = 0; n < 4; ++n) {
        const long col = bn0 + wc * 64 + n * 16 + l15;
#pragma unroll
        for (int r = 0; r < 4; ++r) {
          const float v = acc[m][n][r];
          Ybf[(row0 + r) * N + col] = f2bu(v);
          sk[m * 4 + r] += v * v;
        }
      }
    }
#pragma unroll
    for (int i = 0; i < 32; ++i) {
#pragma unroll
      for (int off = 1; off < 16; off <<= 1)
        sk[i] += __shfl_xor(sk[i], off, 64);
    }
    if (l15 == 0) {
#pragma unroll
      for (int m = 0; m < 8; ++m)
#pragma unroll
        for (int r = 0; r < 4; ++r)
          atomicAdd(&nsq[bm0 + wr * 128 + m * 16 + lg * 4 + r], sk[m * 4 + r]);
    }
  } else {
#pragma unroll
    for (int m = 0; m < 8; ++m) {
      const long row0 = bm0 + wr * 128 + m * 16 + lg * 4;
      float rq[4];
      if constexpr (MODE == G_WO) {
#pragma unroll
        for (int r = 0; r < 4; ++r)
          rq[r] = 1.f / fmaxf(sqrtf(nsqIn[row0 + r]), 1e-12f);
      }
#pragma unroll
      for (int n = 0; n < 4; ++n) {
        const long col = bn0 + wc * 64 + n * 16 + l15;
#pragma unroll
        for (int r = 0; r < 4; ++r) {
          const long idx = (row0 + r) * N + col;
          const float v = acc[m][n][r];
          if constexpr (MODE == G_WO) {
            Ybf[idx] = f2bu(v * rq[r] + resf[idx]);
          } else if constexpr (MODE == G_FFN1) {
            float o = v + bias[col];
            o = o > 0.f ? o : 0.f;
            Ybf[idx] = f2bu(o);
          } else {  // G_FFN2
            Yf[idx] = v + bias[col] + bfu(resb[idx]);
          }
        }
      }
    }
  }
#undef STAGE
#undef LDA
#undef LDB
}

extern "C" void kernel_launch(void* const* d_in, const int* in_sizes, int n_in,
                              void* d_out, int out_size, void* d_ws, size_t ws_size,
                              hipStream_t stream) {
  const float* x  = (const float*)d_in[0];
  const float* wq = (const float*)d_in[1];
  const float* wk = (const float*)d_in[2];
  const float* wv = (const float*)d_in[3];
  const float* wo = (const float*)d_in[4];
  const float* w1 = (const float*)d_in[5];
  const float* b1 = (const float*)d_in[6];
  const float* w2 = (const float*)d_in[7];
  const float* b2 = (const float*)d_in[8];
  float* out = (float*)d_out;

  // workspace carve-up: ~197 MB peak
  char* p = (char*)d_ws;
  auto take = [&](size_t bytes) {
    char* r = p; p += (bytes + 255) & ~(size_t)255; return r;
  };
  u16*   xb   = (u16*)take((size_t)Mm * Dd * 2);    // x bf16; later attn bf16
  u16*   wkT  = (u16*)take((size_t)DIi * Dd * 2);
  u16*   wqT  = (u16*)take((size_t)DIi * Dd * 2);
  u16*   wvT  = (u16*)take((size_t)DIi * Dd * 2);
  u16*   woT  = (u16*)take((size_t)Dd * DIi * 2);
  u16*   w1T  = (u16*)take((size_t)DIi * Dd * 2);
  u16*   w2T  = (u16*)take((size_t)Dd * DIi * 2);
  u16*   wob  = (u16*)take((size_t)Bb * Dd * DIi * 2);  // 16.8 MB
  u16*   buf1 = (u16*)take((size_t)Mm * DIi * 2);   // K, then Q, then h
  float* nksq = (float*)take((size_t)Mm * 4);       // contiguous with next two
  float* nqsq = (float*)take((size_t)Mm * 4);
  float* kvp  = (float*)take((size_t)Bb * DIi * 4);
  (void)ws_size; (void)in_sizes; (void)n_in; (void)out_size;

  const dim3 tpB(32, 8);

  // zero nksq+nqsq+kvp in one launch (contiguous: all sizes 256B-multiples)
  zero_f32<<<(2 * Mm + Bb * DIi + 255) / 256, 256, 0, stream>>>(nksq, 2 * Mm + Bb * DIi);

  f32_to_bf16_vec<<<2048, 256, 0, stream>>>(x, xb, (long)Mm * Dd / 4);
  // 4x [512][2048] -> [2048][512]
  transpose_f32_bf16_z<<<dim3(DIi / 32, Dd / 32, 4), tpB, 0, stream>>>(
      wk, wq, wv, w1, wkT, wqT, wvT, w1T, Dd, DIi);
  // 2x [2048][512] -> [512][2048]
  transpose_f32_bf16_z<<<dim3(Dd / 32, DIi / 32, 2), tpB, 0, stream>>>(
      wo, w2, wo, w2, woT, w2T, woT, w2T, DIi, Dd);

  // K = x@wk -> buf1 (bf16) + nksq
  gemm8<G_PROJ><<<dim3(DIi / 256, Mm / 256), 512, 0, stream>>>(
      xb, wkT, DIi, Dd, buf1, nullptr, nullptr, nullptr, nullptr, nksq, nullptr,
      nullptr, nullptr);

  // kv[b,e]: V = x@wv tiles + LDS-staged K re-read + 1/||k||  (K dead after)
  gemm8<G_KV><<<dim3(DIi / 256, Mm / 256), 512, 0, stream>>>(
      xb, wvT, DIi, Dd, nullptr, nullptr, nullptr, nullptr, nullptr, nullptr, nksq,
      buf1, kvp);

  // Q = x@wq -> buf1 (bf16) + nqsq
  gemm8<G_PROJ><<<dim3(DIi / 256, Mm / 256), 512, 0, stream>>>(
      xb, wqT, DIi, Dd, buf1, nullptr, nullptr, nullptr, nullptr, nqsq, nullptr,
      nullptr, nullptr);

  // wob[b] = woT * kv[b]
  build_wob<<<dim3((Dd * DIi / 8 + 255) / 256, Bb), 256, 0, stream>>>(woT, kvp, wob);

  // attn = (q @ wob[b]) * rsqrt(nqsq) + x -> bf16 into xb slot
  gemm8<G_WO><<<dim3(Dd / 256, Mm / 256), 512, 0, stream>>>(
      buf1, wob, Dd, DIi, xb, nullptr, x, nullptr, nullptr, nullptr, nqsq,
      nullptr, nullptr);

  // h = relu(attn @ w1 + b1) -> buf1
  gemm8<G_FFN1><<<dim3(DIi / 256, Mm / 256), 512, 0, stream>>>(
      xb, w1T, DIi, Dd, buf1, nullptr, nullptr, nullptr, b1, nullptr, nullptr,
      nullptr, nullptr);

  // out = h @ w2 + b2 + attn
  gemm8<G_FFN2><<<dim3(Dd / 256, Mm / 256), 512, 0, stream>>>(
      buf1, w2T, Dd, DIi, nullptr, out, nullptr, xb, b2, nullptr, nullptr,
      nullptr, nullptr);
}